// Round 1
// baseline (205.121 us; speedup 1.0000x reference)
//
#include <hip/hip_runtime.h>

#define HID 20

__device__ __forceinline__ float silu_f(float a) {
    // silu(a) = a * sigmoid(a) = a / (1 + exp(-a))
    return __fdividef(a, 1.0f + __expf(-a));
}

__device__ __forceinline__ void layer20(const float* __restrict__ W,
                                        const float* __restrict__ b,
                                        const float* h, float* hn) {
    #pragma unroll
    for (int j = 0; j < HID; ++j) {
        float acc = b[j];
        #pragma unroll
        for (int i = 0; i < HID; ++i)
            acc = fmaf(h[i], W[j * HID + i], acc);
        hn[j] = silu_f(acc);
    }
}

__global__ __launch_bounds__(256) void SpringEquationNN_70102456205450_kernel(
    const float* __restrict__ t,
    const float* __restrict__ W0, const float* __restrict__ b0,
    const float* __restrict__ W1, const float* __restrict__ b1,
    const float* __restrict__ W2, const float* __restrict__ b2,
    const float* __restrict__ W3, const float* __restrict__ b3,
    const float* __restrict__ W4, const float* __restrict__ b4,
    const float* __restrict__ W5, const float* __restrict__ b5,
    const float* __restrict__ W6, const float* __restrict__ b6,
    const float* __restrict__ W7, const float* __restrict__ b7,
    float* __restrict__ out, int n)
{
    int idx = blockIdx.x * blockDim.x + threadIdx.x;
    if (idx >= n) return;

    float x = t[idx];

    float h[HID], hn[HID];

    // Layer 0: 1 -> 20
    #pragma unroll
    for (int j = 0; j < HID; ++j) {
        float a = fmaf(x, W0[j], b0[j]);
        h[j] = silu_f(a);
    }

    // Layers 1..6: 20 -> 20, SiLU
    layer20(W1, b1, h, hn);
    layer20(W2, b2, hn, h);
    layer20(W3, b3, h, hn);
    layer20(W4, b4, hn, h);
    layer20(W5, b5, h, hn);
    layer20(W6, b6, hn, h);

    // Layer 7: 20 -> 1 (no activation)
    float acc = b7[0];
    #pragma unroll
    for (int i = 0; i < HID; ++i)
        acc = fmaf(h[i], W7[i], acc);

    out[idx] = acc;
}

extern "C" void kernel_launch(void* const* d_in, const int* in_sizes, int n_in,
                              void* d_out, int out_size, void* d_ws, size_t ws_size,
                              hipStream_t stream) {
    const float* t  = (const float*)d_in[0];
    const float* W0 = (const float*)d_in[1];
    const float* b0 = (const float*)d_in[2];
    const float* W1 = (const float*)d_in[3];
    const float* b1 = (const float*)d_in[4];
    const float* W2 = (const float*)d_in[5];
    const float* b2 = (const float*)d_in[6];
    const float* W3 = (const float*)d_in[7];
    const float* b3 = (const float*)d_in[8];
    const float* W4 = (const float*)d_in[9];
    const float* b4 = (const float*)d_in[10];
    const float* W5 = (const float*)d_in[11];
    const float* b5 = (const float*)d_in[12];
    const float* W6 = (const float*)d_in[13];
    const float* b6 = (const float*)d_in[14];
    const float* W7 = (const float*)d_in[15];
    const float* b7 = (const float*)d_in[16];
    float* out = (float*)d_out;

    int n = in_sizes[0];  // t is [N,1] -> N elements
    int block = 256;
    int grid = (n + block - 1) / block;
    SpringEquationNN_70102456205450_kernel<<<grid, block, 0, stream>>>(
        t, W0, b0, W1, b1, W2, b2, W3, b3, W4, b4, W5, b5, W6, b6, W7, b7,
        out, n);
}

// Round 2
// 183.857 us; speedup vs baseline: 1.1157x; 1.1157x over previous
//
#include <hip/hip_runtime.h>

#define HID 20

// Native-instruction SiLU: exactly 5 VALU ops
//   v_mul (x * -log2e), v_exp_f32, v_add, v_rcp_f32, v_mul
// vs. ~25 ops for OCML __expf + IEEE divide. Precision ~1 ulp on exp2/rcp,
// far below the 2.9e-3 (8 bf16-ULP) harness threshold.
__device__ __forceinline__ float silu_f(float a) {
    float e = __builtin_amdgcn_exp2f(-1.442695040888963f * a);   // exp(-a)
    float r = __builtin_amdgcn_rcpf(1.0f + e);                   // sigmoid(a)
    return a * r;
}

__device__ __forceinline__ void layer20(const float* __restrict__ W,
                                        const float* __restrict__ b,
                                        const float* h, float* hn) {
    #pragma unroll
    for (int j = 0; j < HID; ++j) {
        float acc = b[j];
        #pragma unroll
        for (int i = 0; i < HID; ++i)
            acc = fmaf(h[i], W[j * HID + i], acc);
        hn[j] = silu_f(acc);
    }
}

// (256, 4): 4 waves/EU min -> 128-VGPR budget. The layer-boundary live set is
// ~45 regs (old h[20] + new hn[j..] + temps); the default heuristic squeezed
// to 24 VGPRs and spilled. 16 waves/CU is plenty: each thread has 20
// independent FMA chains of ILP.
__global__ __launch_bounds__(256, 4) void SpringEquationNN_70102456205450_kernel(
    const float* __restrict__ t,
    const float* __restrict__ W0, const float* __restrict__ b0,
    const float* __restrict__ W1, const float* __restrict__ b1,
    const float* __restrict__ W2, const float* __restrict__ b2,
    const float* __restrict__ W3, const float* __restrict__ b3,
    const float* __restrict__ W4, const float* __restrict__ b4,
    const float* __restrict__ W5, const float* __restrict__ b5,
    const float* __restrict__ W6, const float* __restrict__ b6,
    const float* __restrict__ W7, const float* __restrict__ b7,
    float* __restrict__ out, int n)
{
    int idx = blockIdx.x * blockDim.x + threadIdx.x;
    if (idx >= n) return;

    float x = t[idx];

    float h[HID], hn[HID];

    // Layer 0: 1 -> 20
    #pragma unroll
    for (int j = 0; j < HID; ++j) {
        float a = fmaf(x, W0[j], b0[j]);
        h[j] = silu_f(a);
    }

    // Layers 1..6: 20 -> 20, SiLU
    layer20(W1, b1, h, hn);
    layer20(W2, b2, hn, h);
    layer20(W3, b3, h, hn);
    layer20(W4, b4, hn, h);
    layer20(W5, b5, h, hn);
    layer20(W6, b6, hn, h);

    // Layer 7: 20 -> 1 (no activation)
    float acc = b7[0];
    #pragma unroll
    for (int i = 0; i < HID; ++i)
        acc = fmaf(h[i], W7[i], acc);

    out[idx] = acc;
}

extern "C" void kernel_launch(void* const* d_in, const int* in_sizes, int n_in,
                              void* d_out, int out_size, void* d_ws, size_t ws_size,
                              hipStream_t stream) {
    const float* t  = (const float*)d_in[0];
    const float* W0 = (const float*)d_in[1];
    const float* b0 = (const float*)d_in[2];
    const float* W1 = (const float*)d_in[3];
    const float* b1 = (const float*)d_in[4];
    const float* W2 = (const float*)d_in[5];
    const float* b2 = (const float*)d_in[6];
    const float* W3 = (const float*)d_in[7];
    const float* b3 = (const float*)d_in[8];
    const float* W4 = (const float*)d_in[9];
    const float* b4 = (const float*)d_in[10];
    const float* W5 = (const float*)d_in[11];
    const float* b5 = (const float*)d_in[12];
    const float* W6 = (const float*)d_in[13];
    const float* b6 = (const float*)d_in[14];
    const float* W7 = (const float*)d_in[15];
    const float* b7 = (const float*)d_in[16];
    float* out = (float*)d_out;

    int n = in_sizes[0];  // t is [N,1] -> N elements
    int block = 256;
    int grid = (n + block - 1) / block;
    SpringEquationNN_70102456205450_kernel<<<grid, block, 0, stream>>>(
        t, W0, b0, W1, b1, W2, b2, W3, b3, W4, b4, W5, b5, W6, b6, W7, b7,
        out, n);
}

// Round 3
// 180.950 us; speedup vs baseline: 1.1336x; 1.0161x over previous
//
#include <hip/hip_runtime.h>

#define HID 20

// Native-instruction SiLU: v_mul, v_exp_f32, v_add, v_rcp_f32, v_mul (5 VALU).
// Saturates correctly: a<<0 -> e=inf -> rcp=0 -> 0;  a>>0 -> e=0 -> a.
__device__ __forceinline__ float silu_f(float a) {
    float e = __builtin_amdgcn_exp2f(-1.442695040888963f * a);   // exp(-a)
    float r = __builtin_amdgcn_rcpf(1.0f + e);                   // sigmoid(a)
    return a * r;
}

// One output row: b[j] + sum_i I_i * W[20j+i], as a chained fmaf expression.
// All weight indices are compile-time constants off a uniform pointer ->
// s_load into SGPRs; each MAC is one v_fmac_f32 with an SGPR weight operand.
#define ROW20(W, b, j, I) \
  fmaf(I##19, (W)[20*(j)+19], fmaf(I##18, (W)[20*(j)+18], \
  fmaf(I##17, (W)[20*(j)+17], fmaf(I##16, (W)[20*(j)+16], \
  fmaf(I##15, (W)[20*(j)+15], fmaf(I##14, (W)[20*(j)+14], \
  fmaf(I##13, (W)[20*(j)+13], fmaf(I##12, (W)[20*(j)+12], \
  fmaf(I##11, (W)[20*(j)+11], fmaf(I##10, (W)[20*(j)+10], \
  fmaf(I##9,  (W)[20*(j)+9],  fmaf(I##8,  (W)[20*(j)+8],  \
  fmaf(I##7,  (W)[20*(j)+7],  fmaf(I##6,  (W)[20*(j)+6],  \
  fmaf(I##5,  (W)[20*(j)+5],  fmaf(I##4,  (W)[20*(j)+4],  \
  fmaf(I##3,  (W)[20*(j)+3],  fmaf(I##2,  (W)[20*(j)+2],  \
  fmaf(I##1,  (W)[20*(j)+1],  fmaf(I##0,  (W)[20*(j)+0], (b)[j]))))))))))))))))))))

// Full 20->20 layer with SiLU: declares fresh scalars O##0..O##19.
// NO local arrays anywhere -> nothing for SROA to miss -> zero scratch.
#define LAYER20(W, b, I, O) \
  float O##0  = silu_f(ROW20(W, b, 0,  I)); \
  float O##1  = silu_f(ROW20(W, b, 1,  I)); \
  float O##2  = silu_f(ROW20(W, b, 2,  I)); \
  float O##3  = silu_f(ROW20(W, b, 3,  I)); \
  float O##4  = silu_f(ROW20(W, b, 4,  I)); \
  float O##5  = silu_f(ROW20(W, b, 5,  I)); \
  float O##6  = silu_f(ROW20(W, b, 6,  I)); \
  float O##7  = silu_f(ROW20(W, b, 7,  I)); \
  float O##8  = silu_f(ROW20(W, b, 8,  I)); \
  float O##9  = silu_f(ROW20(W, b, 9,  I)); \
  float O##10 = silu_f(ROW20(W, b, 10, I)); \
  float O##11 = silu_f(ROW20(W, b, 11, I)); \
  float O##12 = silu_f(ROW20(W, b, 12, I)); \
  float O##13 = silu_f(ROW20(W, b, 13, I)); \
  float O##14 = silu_f(ROW20(W, b, 14, I)); \
  float O##15 = silu_f(ROW20(W, b, 15, I)); \
  float O##16 = silu_f(ROW20(W, b, 16, I)); \
  float O##17 = silu_f(ROW20(W, b, 17, I)); \
  float O##18 = silu_f(ROW20(W, b, 18, I)); \
  float O##19 = silu_f(ROW20(W, b, 19, I));

// Layer 0 (1 -> 20): O_j = silu(x*W[j] + b[j])
#define LAYER0(W, b, O) \
  float O##0  = silu_f(fmaf(x, (W)[0],  (b)[0]));  \
  float O##1  = silu_f(fmaf(x, (W)[1],  (b)[1]));  \
  float O##2  = silu_f(fmaf(x, (W)[2],  (b)[2]));  \
  float O##3  = silu_f(fmaf(x, (W)[3],  (b)[3]));  \
  float O##4  = silu_f(fmaf(x, (W)[4],  (b)[4]));  \
  float O##5  = silu_f(fmaf(x, (W)[5],  (b)[5]));  \
  float O##6  = silu_f(fmaf(x, (W)[6],  (b)[6]));  \
  float O##7  = silu_f(fmaf(x, (W)[7],  (b)[7]));  \
  float O##8  = silu_f(fmaf(x, (W)[8],  (b)[8]));  \
  float O##9  = silu_f(fmaf(x, (W)[9],  (b)[9]));  \
  float O##10 = silu_f(fmaf(x, (W)[10], (b)[10])); \
  float O##11 = silu_f(fmaf(x, (W)[11], (b)[11])); \
  float O##12 = silu_f(fmaf(x, (W)[12], (b)[12])); \
  float O##13 = silu_f(fmaf(x, (W)[13], (b)[13])); \
  float O##14 = silu_f(fmaf(x, (W)[14], (b)[14])); \
  float O##15 = silu_f(fmaf(x, (W)[15], (b)[15])); \
  float O##16 = silu_f(fmaf(x, (W)[16], (b)[16])); \
  float O##17 = silu_f(fmaf(x, (W)[17], (b)[17])); \
  float O##18 = silu_f(fmaf(x, (W)[18], (b)[18])); \
  float O##19 = silu_f(fmaf(x, (W)[19], (b)[19]));

// (256, 4): cap at 4 waves/EU -> 128-VGPR budget; live set is ~45-60 floats,
// so zero spill with headroom.
__global__ __launch_bounds__(256, 4) void SpringEquationNN_70102456205450_kernel(
    const float* __restrict__ t,
    const float* __restrict__ W0, const float* __restrict__ b0,
    const float* __restrict__ W1, const float* __restrict__ b1,
    const float* __restrict__ W2, const float* __restrict__ b2,
    const float* __restrict__ W3, const float* __restrict__ b3,
    const float* __restrict__ W4, const float* __restrict__ b4,
    const float* __restrict__ W5, const float* __restrict__ b5,
    const float* __restrict__ W6, const float* __restrict__ b6,
    const float* __restrict__ W7, const float* __restrict__ b7,
    float* __restrict__ out, int n)
{
    int idx = blockIdx.x * blockDim.x + threadIdx.x;
    if (idx >= n) return;

    float x = t[idx];

    LAYER0 (W0, b0, a)       // x -> a0..a19
    LAYER20(W1, b1, a, c)    // a -> c
    LAYER20(W2, b2, c, d)    // c -> d
    LAYER20(W3, b3, d, e)    // d -> e
    LAYER20(W4, b4, e, f)    // e -> f
    LAYER20(W5, b5, f, g)    // f -> g
    LAYER20(W6, b6, g, p)    // g -> p

    // Layer 7: 20 -> 1, no activation. W7 is [1][20], b7 is [1].
    float acc = ROW20(W7, b7, 0, p);
    out[idx] = acc;
}

extern "C" void kernel_launch(void* const* d_in, const int* in_sizes, int n_in,
                              void* d_out, int out_size, void* d_ws, size_t ws_size,
                              hipStream_t stream) {
    const float* t  = (const float*)d_in[0];
    const float* W0 = (const float*)d_in[1];
    const float* b0 = (const float*)d_in[2];
    const float* W1 = (const float*)d_in[3];
    const float* b1 = (const float*)d_in[4];
    const float* W2 = (const float*)d_in[5];
    const float* b2 = (const float*)d_in[6];
    const float* W3 = (const float*)d_in[7];
    const float* b3 = (const float*)d_in[8];
    const float* W4 = (const float*)d_in[9];
    const float* b4 = (const float*)d_in[10];
    const float* W5 = (const float*)d_in[11];
    const float* b5 = (const float*)d_in[12];
    const float* W6 = (const float*)d_in[13];
    const float* b6 = (const float*)d_in[14];
    const float* W7 = (const float*)d_in[15];
    const float* b7 = (const float*)d_in[16];
    float* out = (float*)d_out;

    int n = in_sizes[0];  // t is [N,1] -> N elements
    int block = 256;
    int grid = (n + block - 1) / block;
    SpringEquationNN_70102456205450_kernel<<<grid, block, 0, stream>>>(
        t, W0, b0, W1, b1, W2, b2, W3, b3, W4, b4, W5, b5, W6, b6, W7, b7,
        out, n);
}

// Round 4
// 155.515 us; speedup vs baseline: 1.3190x; 1.1635x over previous
//
#include <hip/hip_runtime.h>

#define HID 20

typedef float v2f __attribute__((ext_vector_type(2)));

// Native-instruction SiLU on a packed pair. exp/rcp are scalar trans ops
// (quarter-rate, no packed form); the muls/adds around them can pack.
__device__ __forceinline__ v2f silu2(v2f a) {
    float e0 = __builtin_amdgcn_exp2f(-1.442695040888963f * a.x);  // exp(-a0)
    float e1 = __builtin_amdgcn_exp2f(-1.442695040888963f * a.y);  // exp(-a1)
    v2f r;
    r.x = a.x * __builtin_amdgcn_rcpf(1.0f + e0);
    r.y = a.y * __builtin_amdgcn_rcpf(1.0f + e1);
    return r;
}

// 20->20 layer on a pair of points. Weight is wave-uniform (SGPR); the v2f
// splat lowers to VOP3P op_sel broadcast, so each MAC is ONE v_pk_fma_f32
// doing both points. Row-major weight walk keeps s_load_dwordx16-friendly
// contiguous scalar loads.
__device__ __forceinline__ void layer20(const float* __restrict__ W,
                                        const float* __restrict__ b,
                                        const v2f* h, v2f* hn) {
    #pragma unroll
    for (int j = 0; j < HID; ++j) {
        float bj = b[j];
        v2f acc = {bj, bj};
        #pragma unroll
        for (int i = 0; i < HID; ++i) {
            float w = W[j * HID + i];
            acc = __builtin_elementwise_fma(h[i], (v2f){w, w}, acc);
        }
        hn[j] = silu2(acc);
    }
}

// Live set: 20 h-pairs (40 VGPR) + accs in flight + temps ~ 90-110 VGPRs.
// (256,4): 4 waves/EU floor -> 128-VGPR budget; forces the allocator out of
// the 24-VGPR shuffle-heavy schedule seen in R1-R3.
__global__ __launch_bounds__(256, 4) void SpringEquationNN_70102456205450_kernel(
    const float* __restrict__ t,
    const float* __restrict__ W0, const float* __restrict__ b0,
    const float* __restrict__ W1, const float* __restrict__ b1,
    const float* __restrict__ W2, const float* __restrict__ b2,
    const float* __restrict__ W3, const float* __restrict__ b3,
    const float* __restrict__ W4, const float* __restrict__ b4,
    const float* __restrict__ W5, const float* __restrict__ b5,
    const float* __restrict__ W6, const float* __restrict__ b6,
    const float* __restrict__ W7, const float* __restrict__ b7,
    float* __restrict__ out, int n)
{
    int idx = blockIdx.x * blockDim.x + threadIdx.x;   // pair index
    int p0 = 2 * idx;
    if (p0 >= n) return;

    // Coalesced 8B load of two consecutive points (N is even: 1048576).
    v2f x = *(const v2f*)(t + p0);

    v2f h[HID], hn[HID];

    // Layer 0: 1 -> 20 on both points
    #pragma unroll
    for (int j = 0; j < HID; ++j) {
        float w = W0[j], bb = b0[j];
        v2f a = __builtin_elementwise_fma(x, (v2f){w, w}, (v2f){bb, bb});
        h[j] = silu2(a);
    }

    // Layers 1..6: 20 -> 20, SiLU
    layer20(W1, b1, h, hn);
    layer20(W2, b2, hn, h);
    layer20(W3, b3, h, hn);
    layer20(W4, b4, hn, h);
    layer20(W5, b5, h, hn);
    layer20(W6, b6, hn, h);

    // Layer 7: 20 -> 1 (no activation)
    float b7v = b7[0];
    v2f acc = {b7v, b7v};
    #pragma unroll
    for (int i = 0; i < HID; ++i) {
        float w = W7[i];
        acc = __builtin_elementwise_fma(h[i], (v2f){w, w}, acc);
    }

    // Coalesced 8B store.
    *(v2f*)(out + p0) = acc;
}

extern "C" void kernel_launch(void* const* d_in, const int* in_sizes, int n_in,
                              void* d_out, int out_size, void* d_ws, size_t ws_size,
                              hipStream_t stream) {
    const float* t  = (const float*)d_in[0];
    const float* W0 = (const float*)d_in[1];
    const float* b0 = (const float*)d_in[2];
    const float* W1 = (const float*)d_in[3];
    const float* b1 = (const float*)d_in[4];
    const float* W2 = (const float*)d_in[5];
    const float* b2 = (const float*)d_in[6];
    const float* W3 = (const float*)d_in[7];
    const float* b3 = (const float*)d_in[8];
    const float* W4 = (const float*)d_in[9];
    const float* b4 = (const float*)d_in[10];
    const float* W5 = (const float*)d_in[11];
    const float* b5 = (const float*)d_in[12];
    const float* W6 = (const float*)d_in[13];
    const float* b6 = (const float*)d_in[14];
    const float* W7 = (const float*)d_in[15];
    const float* b7 = (const float*)d_in[16];
    float* out = (float*)d_out;

    int n = in_sizes[0];             // N points
    int pairs = (n + 1) / 2;         // threads (N=1048576 -> 524288)
    int block = 256;
    int grid = (pairs + block - 1) / block;
    SpringEquationNN_70102456205450_kernel<<<grid, block, 0, stream>>>(
        t, W0, b0, W1, b1, W2, b2, W3, b3, W4, b4, W5, b5, W6, b6, W7, b7,
        out, n);
}